// Round 8
// baseline (426.671 us; speedup 1.0000x reference)
//
#include <hip/hip_runtime.h>

#define B_ 4
#define S_ 2048
#define D_ 1024
#define H_ 16
#define HD_ 64
#define M_ 8192  // B_*S_

typedef __attribute__((ext_vector_type(8))) short          bf16x8;
typedef __attribute__((ext_vector_type(8))) unsigned short u16x8;
typedef __attribute__((ext_vector_type(4))) float          f32x4;

#define MFMA16(a, b, c) __builtin_amdgcn_mfma_f32_16x16x32_bf16((a), (b), (c), 0, 0, 0)

// exp(s/8) = exp2(s * 0.125*log2(e)).  SCL is folded into Q at projection
// time, so both attention passes compute exp2(s') directly and stay
// mutually consistent (l and the attn-mean numerator use the same s').
#define SCL 0.18033688011112042f

__device__ __forceinline__ unsigned short f2b(float f) {  // RTNE fp32->bf16
    unsigned int u = __float_as_uint(f);
    return (unsigned short)((u + 0x7fffu + ((u >> 16) & 1u)) >> 16);
}

__device__ __forceinline__ unsigned int cvtpk_bf16(float lo, float hi) {
    unsigned int r;
    asm("v_cvt_pk_bf16_f32 %0, %1, %2" : "=v"(r) : "v"(lo), "v"(hi));
    return r;  // low u16 = bf16(lo), high u16 = bf16(hi)  (RTNE)
}

// XOR-swizzled address into a [64][64]-u16 LDS tile: byte ^= (row&7)<<4.
// Bijective within each 128B row; keeps 16B/8B alignment; spreads the
// row-stride-128B bank pattern so all access classes are <=2-way.
__device__ __forceinline__ unsigned short* swz64(unsigned short* base, int row, int col) {
    unsigned off = ((unsigned)row << 7) + ((unsigned)col << 1);
    off ^= (unsigned)((row & 7) << 4);
    return (unsigned short*)((char*)base + off);
}

// ---------------------------------------------------------------------------
// K0: fp32 -> bf16 casts.
// ---------------------------------------------------------------------------
__global__ __launch_bounds__(256) void cast_k(const float* __restrict__ src,
                                              unsigned short* __restrict__ dst, int n) {
    int i = (blockIdx.x * 256 + threadIdx.x) * 4;
    if (i >= n) return;
    float4 v = *(const float4*)(src + i);
    ushort4 o;
    o.x = f2b(v.x); o.y = f2b(v.y); o.z = f2b(v.z); o.w = f2b(v.w);
    *(ushort4*)(dst + i) = o;
}

__global__ __launch_bounds__(256) void cast3_k(
    const float* __restrict__ s0, const float* __restrict__ s1, const float* __restrict__ s2,
    unsigned short* __restrict__ d0, unsigned short* __restrict__ d1,
    unsigned short* __restrict__ d2, int n) {
    const float* src = (blockIdx.y == 0) ? s0 : (blockIdx.y == 1) ? s1 : s2;
    unsigned short* dst = (blockIdx.y == 0) ? d0 : (blockIdx.y == 1) ? d1 : d2;
    int i = (blockIdx.x * 256 + threadIdx.x) * 4;
    if (i >= n) return;
    float4 v = *(const float4*)(src + i);
    ushort4 o;
    o.x = f2b(v.x); o.y = f2b(v.y); o.z = f2b(v.z); o.w = f2b(v.w);
    *(ushort4*)(dst + i) = o;
}

// ---------------------------------------------------------------------------
// K1: QKV projection, bf16 MFMA.  y = x @ W.T + b, W row-major [n][k].
// 128x128 tile, BK=64, 4 waves (2x2), 64x64 per wave = 4x4 frags of 16x16.
// Q output PRE-SCALED by SCL, layout [B][H][S][HD].  K layout [B][H][S][HD].
// V written TRANSPOSED: VT[B][H][HD][S].
// ---------------------------------------------------------------------------
__global__ __launch_bounds__(256) void qkv_gemm_k(
    const unsigned short* __restrict__ xb,
    const unsigned short* __restrict__ wb0, const unsigned short* __restrict__ wb1,
    const unsigned short* __restrict__ wb2,
    const float* __restrict__ bq, const float* __restrict__ bk, const float* __restrict__ bv,
    unsigned short* __restrict__ Qo, unsigned short* __restrict__ Ko,
    unsigned short* __restrict__ VT)
{
    __shared__ unsigned short xs[128][72];
    __shared__ unsigned short wsm[128][72];

    const unsigned short* W; const float* bias;
    if (blockIdx.z == 0)      { W = wb0; bias = bq; }
    else if (blockIdx.z == 1) { W = wb1; bias = bk; }
    else                      { W = wb2; bias = bv; }

    const int m0 = blockIdx.x * 128, n0 = blockIdx.y * 128;
    const int tid = threadIdx.x, lane = tid & 63, wid = tid >> 6;
    const int wm = (wid >> 1) * 64, wn = (wid & 1) * 64;
    const int srow = tid >> 3;          // 0..31
    const int skc  = (tid & 7) * 8;     // bf16 col 0,8,..,56

    f32x4 acc[4][4] = {};

    for (int k0 = 0; k0 < D_; k0 += 64) {
        u16x8 xa[4], wa[4];
        #pragma unroll
        for (int r = 0; r < 4; ++r) {
            int row = srow + 32 * r;
            xa[r] = *(const u16x8*)&xb[(size_t)(m0 + row) * D_ + k0 + skc];
            wa[r] = *(const u16x8*)&W [(size_t)(n0 + row) * D_ + k0 + skc];
        }
        __syncthreads();
        #pragma unroll
        for (int r = 0; r < 4; ++r) {
            int row = srow + 32 * r;
            *(u16x8*)&xs[row][skc]  = xa[r];
            *(u16x8*)&wsm[row][skc] = wa[r];
        }
        __syncthreads();
        #pragma unroll
        for (int kd = 0; kd < 2; ++kd) {
            const int kc = 32 * kd + 8 * (lane >> 4);
            bf16x8 af[4], bfr[4];
            #pragma unroll
            for (int mf = 0; mf < 4; ++mf)
                af[mf] = *(const bf16x8*)&xs[wm + 16 * mf + (lane & 15)][kc];
            #pragma unroll
            for (int nf = 0; nf < 4; ++nf)
                bfr[nf] = *(const bf16x8*)&wsm[wn + 16 * nf + (lane & 15)][kc];
            #pragma unroll
            for (int mf = 0; mf < 4; ++mf)
                #pragma unroll
                for (int nf = 0; nf < 4; ++nf)
                    acc[mf][nf] = MFMA16(af[mf], bfr[nf], acc[mf][nf]);
        }
    }

    const int col_l = lane & 15, rgrp = lane >> 4;
    if (blockIdx.z != 2) {
        unsigned short* out = (blockIdx.z == 0) ? Qo : Ko;
        const float oscale = (blockIdx.z == 0) ? SCL : 1.0f;
        #pragma unroll
        for (int nf = 0; nf < 4; ++nf) {
            const int n = n0 + wn + 16 * nf + col_l;
            const float bval = bias[n];
            const int h = n >> 6, d = n & 63;
            #pragma unroll
            for (int mf = 0; mf < 4; ++mf)
                #pragma unroll
                for (int r = 0; r < 4; ++r) {
                    int m = m0 + wm + 16 * mf + 4 * rgrp + r;
                    int bI = m >> 11, s = m & 2047;
                    out[(((size_t)bI * H_ + h) * S_ + s) * HD_ + d]
                        = f2b((acc[mf][nf][r] + bval) * oscale);
                }
        }
    } else {
        #pragma unroll
        for (int nf = 0; nf < 4; ++nf) {
            const int n = n0 + wn + 16 * nf + col_l;
            const float bval = bias[n];
            const int h = n >> 6, d = n & 63;
            #pragma unroll
            for (int mf = 0; mf < 4; ++mf) {
                int m = m0 + wm + 16 * mf + 4 * rgrp;   // 4 consecutive s
                int bI = m >> 11, s = m & 2047;
                ushort4 o;
                o.x = f2b(acc[mf][nf][0] + bval);
                o.y = f2b(acc[mf][nf][1] + bval);
                o.z = f2b(acc[mf][nf][2] + bval);
                o.w = f2b(acc[mf][nf][3] + bval);
                *(ushort4*)&VT[(((size_t)bI * H_ + h) * HD_ + d) * S_ + s] = o;
            }
        }
    }
}

// ---------------------------------------------------------------------------
// K2: attention pass 1 (verified 16x16x32 MFMA only).  Swapped QK^T
// (mfma(K,Q)); P staged per-q-16-block through a [64][64] wave-private LDS
// stripe (same-wave write->read, in-order); V from pre-transposed VT.
// All LDS tiles [64][64] + XOR swizzle -> <=2-way banks, 25.5 KB total
// -> 6 blocks/CU.  Outputs Linv = 1/l and PPOOL (pooled partials).
// ---------------------------------------------------------------------------
__global__ __launch_bounds__(256) void attn_ctx_k(
    const unsigned short* __restrict__ Q, const unsigned short* __restrict__ K,
    const unsigned short* __restrict__ VT,
    float* __restrict__ Linv, float* __restrict__ PPOOL)
{
    __shared__ unsigned short ks0[64 * 64];
    __shared__ unsigned short vt0[64 * 64];   // vt[d][kpos], staged from VT
    __shared__ unsigned short ps0[64 * 64];   // P stripes: rows 16*wid..16*wid+15
    __shared__ float pp[4][64];               // per-wave pooled partials
    __shared__ float lsm[4][32];              // per-wave 1/l by local q-row

    // XCD swizzle: lin = (g&7) + 8*qb + 128*(g>>3)  (bijective, 1024 blocks)
    const int lin = blockIdx.x;
    const int g   = (lin & 7) | ((lin >> 7) << 3);   // bh index 0..63
    const int qb  = (lin >> 3) & 15;
    const int b   = g >> 4, h = g & 15;
    const int q0  = qb * 128;

    const size_t hoff = ((size_t)(b * H_ + h)) * S_ * HD_;
    const unsigned short* Qh  = Q  + hoff;
    const unsigned short* Kh  = K  + hoff;
    const unsigned short* VTh = VT + hoff;   // [HD][S]

    const int tid = threadIdx.x, lane = tid & 63, wid = tid >> 6;
    const int srow = tid >> 3;       // 0..31
    const int skc  = (tid & 7) * 8;
    const int col_l = lane & 15, rgrp = lane >> 4;

    bf16x8 qf[2][2];
    #pragma unroll
    for (int i = 0; i < 2; ++i)
        #pragma unroll
        for (int kd = 0; kd < 2; ++kd)
            qf[i][kd] = *(const bf16x8*)&Qh[(size_t)(q0 + 32 * wid + 16 * i + col_l) * HD_
                                            + 32 * kd + 8 * rgrp];

    f32x4 cacc[2][4] = {};
    float lp[2] = {};

    for (int kb = 0; kb < S_; kb += 64) {
        u16x8 ka[2], va[2];
        #pragma unroll
        for (int r = 0; r < 2; ++r) {
            int row = srow + 32 * r;
            ka[r] = *(const u16x8*)&Kh [(size_t)(kb + row) * HD_ + skc];
            va[r] = *(const u16x8*)&VTh[(size_t)row * S_ + kb + skc];
        }
        __syncthreads();   // everyone done reading previous ks0/vt0
        #pragma unroll
        for (int r = 0; r < 2; ++r) {
            int row = srow + 32 * r;
            *(u16x8*)swz64(ks0, row, skc) = ka[r];
            *(u16x8*)swz64(vt0, row, skc) = va[r];
        }
        __syncthreads();

        #pragma unroll
        for (int i = 0; i < 2; ++i) {
            // S^T = K Q^T: lane (c,g) reg r = P[q=c][k=16n+4g+r]
            unsigned int w[8];
            #pragma unroll
            for (int n = 0; n < 4; ++n) {
                f32x4 s = {};
                #pragma unroll
                for (int kd = 0; kd < 2; ++kd) {
                    bf16x8 kf = *(const bf16x8*)swz64(ks0, 16 * n + col_l, 32 * kd + 8 * rgrp);
                    s = MFMA16(kf, qf[i][kd], s);
                }
                float e0 = exp2f(s[0]), e1 = exp2f(s[1]);
                float e2 = exp2f(s[2]), e3 = exp2f(s[3]);
                lp[i] += (e0 + e1) + (e2 + e3);
                w[2 * n]     = cvtpk_bf16(e0, e1);
                w[2 * n + 1] = cvtpk_bf16(e2, e3);
            }
            // stage P stripe: ps[16*wid + q][k]  (wave-private 16 rows)
            #pragma unroll
            for (int n = 0; n < 4; ++n) {
                uint2 wpair = { w[2 * n], w[2 * n + 1] };
                *(uint2*)swz64(ps0, 16 * wid + col_l, 16 * n + 4 * rgrp) = wpair;
            }
            // ctx += P @ V  (same-wave LDS RAW, in-order)
            #pragma unroll
            for (int kk = 0; kk < 2; ++kk) {
                bf16x8 pa = *(const bf16x8*)swz64(ps0, 16 * wid + col_l, 32 * kk + 8 * rgrp);
                #pragma unroll
                for (int nd = 0; nd < 4; ++nd) {
                    bf16x8 vf = *(const bf16x8*)swz64(vt0, 16 * nd + col_l, 32 * kk + 8 * rgrp);
                    cacc[i][nd] = MFMA16(pa, vf, cacc[i][nd]);
                }
            }
        }
    }

    // reduce l over the 4 rgrp lane groups (each holds a disjoint k-subset)
    #pragma unroll
    for (int i = 0; i < 2; ++i) {
        float v = lp[i];
        v += __shfl_xor(v, 16); v += __shfl_xor(v, 32);
        lp[i] = v;
    }
    if (lane < 16) {
        #pragma unroll
        for (int i = 0; i < 2; ++i) {
            float inv = 1.0f / lp[i];
            Linv[((size_t)(b * H_ + h)) * S_ + q0 + 32 * wid + 16 * i + lane] = inv;
            lsm[wid][16 * i + lane] = inv;
        }
    }

    // pooled partial: sum over this wave's 32 q-rows of cacc * (1/l)
    float pool4[4] = {};
    #pragma unroll
    for (int i = 0; i < 2; ++i)
        #pragma unroll
        for (int r = 0; r < 4; ++r) {
            float inv = lsm[wid][16 * i + 4 * rgrp + r];
            #pragma unroll
            for (int n = 0; n < 4; ++n)
                pool4[n] = fmaf(cacc[i][n][r], inv, pool4[n]);
        }
    #pragma unroll
    for (int n = 0; n < 4; ++n) {
        float v = pool4[n];
        v += __shfl_xor(v, 16); v += __shfl_xor(v, 32);
        pool4[n] = v;
    }
    if (lane < 16) {
        #pragma unroll
        for (int n = 0; n < 4; ++n) pp[wid][16 * n + lane] = pool4[n];
    }
    __syncthreads();
    if (tid < 64) {
        float s = pp[0][tid] + pp[1][tid] + pp[2][tid] + pp[3][tid];
        PPOOL[((size_t)(b * H_ + h) * (S_ / 128) + qb) * 64 + tid] = s;
    }
}

// ---------------------------------------------------------------------------
// K3: attn_mean[b,q,k] = (1/16) sum_h exp2(s'_h) * Linv_h — second score
// pass.  LDS-staged Q (128x64) and K (64x64) per head; swapped MFMA ->
// dwordx4 stores; Linv is a multiply (no divides).
// ---------------------------------------------------------------------------
__global__ __launch_bounds__(256) void attn_mean_k(
    const unsigned short* __restrict__ Q, const unsigned short* __restrict__ K,
    const float* __restrict__ Linv, float* __restrict__ attn_out)
{
    __shared__ unsigned short qs[128][72];
    __shared__ unsigned short ksm[64][72];
    __shared__ float lsm[128];

    const int k0 = blockIdx.x * 64, q0 = blockIdx.y * 128, b = blockIdx.z;
    const int tid = threadIdx.x, lane = tid & 63, wid = tid >> 6;
    const int col_l = lane & 15, rgrp = lane >> 4;
    const int qrow = tid >> 1, qcol = (tid & 1) * 32;   // Q staging: 32 elems/thread
    const int krow = tid >> 2, kcol = (tid & 3) * 16;   // K staging: 16 elems/thread

    f32x4 macc[4][2] = {};   // [n: k-16-block][i: q-16-block]

    for (int h = 0; h < H_; ++h) {
        const size_t hoff = ((size_t)(b * H_ + h)) * S_ * HD_;
        const unsigned short* Qh = Q + hoff;
        const unsigned short* Kh = K + hoff;

        u16x8 qa[4], ka[2];
        #pragma unroll
        for (int j = 0; j < 4; ++j)
            qa[j] = *(const u16x8*)&Qh[(size_t)(q0 + qrow) * HD_ + qcol + 8 * j];
        #pragma unroll
        for (int j = 0; j < 2; ++j)
            ka[j] = *(const u16x8*)&Kh[(size_t)(k0 + krow) * HD_ + kcol + 8 * j];
        float lval = 0.f;
        if (tid < 128) lval = Linv[((size_t)(b * H_ + h)) * S_ + q0 + tid];

        __syncthreads();   // previous head's compute done
        #pragma unroll
        for (int j = 0; j < 4; ++j) *(u16x8*)&qs[qrow][qcol + 8 * j] = qa[j];
        #pragma unroll
        for (int j = 0; j < 2; ++j) *(u16x8*)&ksm[krow][kcol + 8 * j] = ka[j];
        if (tid < 128) lsm[tid] = lval;
        __syncthreads();

        bf16x8 qf[2][2];
        #pragma unroll
        for (int i = 0; i < 2; ++i)
            #pragma unroll
            for (int kd = 0; kd < 2; ++kd)
                qf[i][kd] = *(const bf16x8*)&qs[32 * wid + 16 * i + col_l][32 * kd + 8 * rgrp];

        float li0 = lsm[32 * wid + col_l] * 0.0625f;
        float li1 = lsm[32 * wid + 16 + col_l] * 0.0625f;

        #pragma unroll
        for (int n = 0; n < 4; ++n) {
            f32x4 s0 = {}, s1 = {};
            #pragma unroll
            for (int kd = 0; kd < 2; ++kd) {
                bf16x8 kf = *(const bf16x8*)&ksm[16 * n + col_l][32 * kd + 8 * rgrp];
                s0 = MFMA16(kf, qf[0][kd], s0);
                s1 = MFMA16(kf, qf[1][kd], s1);
            }
            #pragma unroll
            for (int r = 0; r < 4; ++r) {
                macc[n][0][r] = fmaf(exp2f(s0[r]), li0, macc[n][0][r]);
                macc[n][1][r] = fmaf(exp2f(s1[r]), li1, macc[n][1][r]);
            }
        }
    }

    #pragma unroll
    for (int n = 0; n < 4; ++n)
        #pragma unroll
        for (int i = 0; i < 2; ++i) {
            int q = q0 + 32 * wid + 16 * i + col_l;
            *(f32x4*)&attn_out[((size_t)b * S_ + q) * S_ + k0 + 16 * n + 4 * rgrp]
                = macc[n][i];
        }
}

// ---------------------------------------------------------------------------
// K4: out[b,j] = pooled[b,:] . wo[j,:] + bo[j], pooled reduced from PPOOL.
// ---------------------------------------------------------------------------
__global__ __launch_bounds__(256) void out_k(
    const float* __restrict__ PPOOL, const float* __restrict__ wo,
    const float* __restrict__ bo, float* __restrict__ out)
{
    __shared__ float psm[D_];
    const int b = blockIdx.x >> 2;
    for (int d = threadIdx.x; d < D_; d += 256) {
        const float* pp = PPOOL + ((size_t)(b * H_ + (d >> 6)) * (S_ / 128)) * 64 + (d & 63);
        float s = 0.f;
        #pragma unroll
        for (int qb = 0; qb < S_ / 128; ++qb) s += pp[qb * 64];
        psm[d] = s * (1.0f / S_);
    }
    __syncthreads();
    const int j = (blockIdx.x & 3) * 256 + threadIdx.x;
    float sum = bo[j];
    const float* wr = wo + (size_t)j * D_;
    for (int d = 0; d < D_; d += 4) {
        float4 w4 = *(const float4*)&wr[d];
        sum += psm[d] * w4.x + psm[d+1] * w4.y + psm[d+2] * w4.z + psm[d+3] * w4.w;
    }
    out[b * D_ + j] = sum;
}

// ---------------------------------------------------------------------------
extern "C" void kernel_launch(void* const* d_in, const int* in_sizes, int n_in,
                              void* d_out, int out_size, void* d_ws, size_t ws_size,
                              hipStream_t stream)
{
    const float* x  = (const float*)d_in[0];
    const float* wq = (const float*)d_in[1];
    const float* bq = (const float*)d_in[2];
    const float* wk = (const float*)d_in[3];
    const float* bk = (const float*)d_in[4];
    const float* wv = (const float*)d_in[5];
    const float* bv = (const float*)d_in[6];
    const float* wo = (const float*)d_in[7];
    const float* bo = (const float*)d_in[8];
    float* out = (float*)d_out;

    char* ws = (char*)d_ws;
    const size_t XN  = (size_t)M_ * D_;            // 8,388,608
    const size_t WN  = (size_t)D_ * D_;            // 1,048,576
    const size_t QN  = (size_t)B_ * H_ * S_ * HD_; // 8,388,608

    unsigned short* xb  = (unsigned short*)ws;                 ws += XN * 2;   // 16 MB
    unsigned short* wqb = (unsigned short*)ws;                 ws += WN * 2;   // 2 MB
    unsigned short* wkb = (unsigned short*)ws;                 ws += WN * 2;
    unsigned short* wvb = (unsigned short*)ws;                 ws += WN * 2;
    unsigned short* Qb  = (unsigned short*)ws;                 ws += QN * 2;   // 16 MB
    unsigned short* Kb  = (unsigned short*)ws;                 ws += QN * 2;
    unsigned short* VTb = (unsigned short*)ws;                 ws += QN * 2;   // [B][H][HD][S]
    float* Lb    = (float*)ws;                                 ws += (size_t)B_ * H_ * S_ * 4;
    float* PPOOL = (float*)ws;   // B*H*(S/128)*64 = 65536 floats = 256 KB

    cast_k<<<dim3(XN / 1024), 256, 0, stream>>>(x, xb, (int)XN);
    cast3_k<<<dim3(WN / 1024, 3), 256, 0, stream>>>(wq, wk, wv, wqb, wkb, wvb, (int)WN);

    qkv_gemm_k<<<dim3(M_ / 128, D_ / 128, 3), 256, 0, stream>>>(
        xb, wqb, wkb, wvb, bq, bk, bv, Qb, Kb, VTb);
    attn_ctx_k<<<dim3(1024), 256, 0, stream>>>(Qb, Kb, VTb, Lb, PPOOL);
    attn_mean_k<<<dim3(S_ / 64, S_ / 128, B_), 256, 0, stream>>>(Qb, Kb, Lb, out + B_ * D_);
    out_k<<<16, 256, 0, stream>>>(PPOOL, wo, bo, out);
}

// Round 10
// 416.982 us; speedup vs baseline: 1.0232x; 1.0232x over previous
//
#include <hip/hip_runtime.h>

#define B_ 4
#define S_ 2048
#define D_ 1024
#define H_ 16
#define HD_ 64
#define M_ 8192  // B_*S_

typedef __attribute__((ext_vector_type(8)))  short          bf16x8;
typedef __attribute__((ext_vector_type(4)))  short          s16x4;
typedef __attribute__((ext_vector_type(8)))  unsigned short u16x8;
typedef __attribute__((ext_vector_type(4)))  float          f32x4;
typedef __attribute__((ext_vector_type(16))) float          f32x16;

#define MFMA16(a, b, c) __builtin_amdgcn_mfma_f32_16x16x32_bf16((a), (b), (c), 0, 0, 0)
#define MFMA32(a, b, c) __builtin_amdgcn_mfma_f32_32x32x16_bf16((a), (b), (c), 0, 0, 0)

// exp(s/8) = exp2(s * 0.125*log2(e)).  SCL is folded into Q at projection
// time, so both attention passes compute exp2(s') directly and stay
// mutually consistent (l and the attn-mean numerator use the same s').
#define SCL 0.18033688011112042f

__device__ __forceinline__ unsigned short f2b(float f) {  // RTNE fp32->bf16
    unsigned int u = __float_as_uint(f);
    return (unsigned short)((u + 0x7fffu + ((u >> 16) & 1u)) >> 16);
}

__device__ __forceinline__ unsigned int cvtpk_bf16(float lo, float hi) {
    unsigned int r;
    asm("v_cvt_pk_bf16_f32 %0, %1, %2" : "=v"(r) : "v"(lo), "v"(hi));
    return r;  // low u16 = bf16(lo), high u16 = bf16(hi)  (RTNE)
}

// XOR-swizzled address into a [64][64]-u16 LDS tile: byte ^= (row&7)<<4.
// Bijective within each 128B row; keeps 16B/8B alignment.
__device__ __forceinline__ unsigned short* swz64(unsigned short* base, int row, int col) {
    unsigned off = ((unsigned)row << 7) + ((unsigned)col << 1);
    off ^= (unsigned)((row & 7) << 4);
    return (unsigned short*)((char*)base + off);
}

// ---------------------------------------------------------------------------
// K0: fp32 -> bf16 casts.
// ---------------------------------------------------------------------------
__global__ __launch_bounds__(256) void cast_k(const float* __restrict__ src,
                                              unsigned short* __restrict__ dst, int n) {
    int i = (blockIdx.x * 256 + threadIdx.x) * 4;
    if (i >= n) return;
    float4 v = *(const float4*)(src + i);
    ushort4 o;
    o.x = f2b(v.x); o.y = f2b(v.y); o.z = f2b(v.z); o.w = f2b(v.w);
    *(ushort4*)(dst + i) = o;
}

__global__ __launch_bounds__(256) void cast3_k(
    const float* __restrict__ s0, const float* __restrict__ s1, const float* __restrict__ s2,
    unsigned short* __restrict__ d0, unsigned short* __restrict__ d1,
    unsigned short* __restrict__ d2, int n) {
    const float* src = (blockIdx.y == 0) ? s0 : (blockIdx.y == 1) ? s1 : s2;
    unsigned short* dst = (blockIdx.y == 0) ? d0 : (blockIdx.y == 1) ? d1 : d2;
    int i = (blockIdx.x * 256 + threadIdx.x) * 4;
    if (i >= n) return;
    float4 v = *(const float4*)(src + i);
    ushort4 o;
    o.x = f2b(v.x); o.y = f2b(v.y); o.z = f2b(v.z); o.w = f2b(v.w);
    *(ushort4*)(dst + i) = o;
}

// ---------------------------------------------------------------------------
// K1: QKV projection, bf16 MFMA.  y = x @ W.T + b, W row-major [n][k].
// 128x128 tile, BK=64, 4 waves (2x2), 64x64 per wave = 4x4 frags of 16x16.
// Q output PRE-SCALED by SCL, layout [B][H][S][HD].  K layout [B][H][S][HD].
// V written TRANSPOSED: VT[B][H][HD][S].
// ---------------------------------------------------------------------------
__global__ __launch_bounds__(256) void qkv_gemm_k(
    const unsigned short* __restrict__ xb,
    const unsigned short* __restrict__ wb0, const unsigned short* __restrict__ wb1,
    const unsigned short* __restrict__ wb2,
    const float* __restrict__ bq, const float* __restrict__ bk, const float* __restrict__ bv,
    unsigned short* __restrict__ Qo, unsigned short* __restrict__ Ko,
    unsigned short* __restrict__ VT)
{
    __shared__ unsigned short xs[128][72];
    __shared__ unsigned short wsm[128][72];

    const unsigned short* W; const float* bias;
    if (blockIdx.z == 0)      { W = wb0; bias = bq; }
    else if (blockIdx.z == 1) { W = wb1; bias = bk; }
    else                      { W = wb2; bias = bv; }

    const int m0 = blockIdx.x * 128, n0 = blockIdx.y * 128;
    const int tid = threadIdx.x, lane = tid & 63, wid = tid >> 6;
    const int wm = (wid >> 1) * 64, wn = (wid & 1) * 64;
    const int srow = tid >> 3;          // 0..31
    const int skc  = (tid & 7) * 8;     // bf16 col 0,8,..,56

    f32x4 acc[4][4] = {};

    for (int k0 = 0; k0 < D_; k0 += 64) {
        u16x8 xa[4], wa[4];
        #pragma unroll
        for (int r = 0; r < 4; ++r) {
            int row = srow + 32 * r;
            xa[r] = *(const u16x8*)&xb[(size_t)(m0 + row) * D_ + k0 + skc];
            wa[r] = *(const u16x8*)&W [(size_t)(n0 + row) * D_ + k0 + skc];
        }
        __syncthreads();
        #pragma unroll
        for (int r = 0; r < 4; ++r) {
            int row = srow + 32 * r;
            *(u16x8*)&xs[row][skc]  = xa[r];
            *(u16x8*)&wsm[row][skc] = wa[r];
        }
        __syncthreads();
        #pragma unroll
        for (int kd = 0; kd < 2; ++kd) {
            const int kc = 32 * kd + 8 * (lane >> 4);
            bf16x8 af[4], bfr[4];
            #pragma unroll
            for (int mf = 0; mf < 4; ++mf)
                af[mf] = *(const bf16x8*)&xs[wm + 16 * mf + (lane & 15)][kc];
            #pragma unroll
            for (int nf = 0; nf < 4; ++nf)
                bfr[nf] = *(const bf16x8*)&wsm[wn + 16 * nf + (lane & 15)][kc];
            #pragma unroll
            for (int mf = 0; mf < 4; ++mf)
                #pragma unroll
                for (int nf = 0; nf < 4; ++nf)
                    acc[mf][nf] = MFMA16(af[mf], bfr[nf], acc[mf][nf]);
        }
    }

    const int col_l = lane & 15, rgrp = lane >> 4;
    if (blockIdx.z != 2) {
        unsigned short* out = (blockIdx.z == 0) ? Qo : Ko;
        const float oscale = (blockIdx.z == 0) ? SCL : 1.0f;
        #pragma unroll
        for (int nf = 0; nf < 4; ++nf) {
            const int n = n0 + wn + 16 * nf + col_l;
            const float bval = bias[n];
            const int h = n >> 6, d = n & 63;
            #pragma unroll
            for (int mf = 0; mf < 4; ++mf)
                #pragma unroll
                for (int r = 0; r < 4; ++r) {
                    int m = m0 + wm + 16 * mf + 4 * rgrp + r;
                    int bI = m >> 11, s = m & 2047;
                    out[(((size_t)bI * H_ + h) * S_ + s) * HD_ + d]
                        = f2b((acc[mf][nf][r] + bval) * oscale);
                }
        }
    } else {
        #pragma unroll
        for (int nf = 0; nf < 4; ++nf) {
            const int n = n0 + wn + 16 * nf + col_l;
            const float bval = bias[n];
            const int h = n >> 6, d = n & 63;
            #pragma unroll
            for (int mf = 0; mf < 4; ++mf) {
                int m = m0 + wm + 16 * mf + 4 * rgrp;   // 4 consecutive s
                int bI = m >> 11, s = m & 2047;
                ushort4 o;
                o.x = f2b(acc[mf][nf][0] + bval);
                o.y = f2b(acc[mf][nf][1] + bval);
                o.z = f2b(acc[mf][nf][2] + bval);
                o.w = f2b(acc[mf][nf][3] + bval);
                *(ushort4*)&VT[(((size_t)bI * H_ + h) * HD_ + d) * S_ + s] = o;
            }
        }
    }
}

// ---------------------------------------------------------------------------
// K2: attention pass 1, 32x32x16 MFMA, P entirely in registers.
// Swapped QK^T (mfma(K,Q)): C/D (m74/m101-verified) gives lane l the P-row
// q=l&31 at k = (reg&3)+8*(reg>>2)+4*(l>>5) (+32*kr).  PV consumes these
// registers directly as the A-operand (8 cvt_pk per 16 values); the k-slot
// permutation is matched on the B side by addressing vt with the same sigma:
// slots 0-3 <- vt[d][32kr+16ks+4h+0..3], slots 4-7 <- +8.  Slot-pairing makes
// this exact.  No P LDS, no cross-lane ops.  LDS = ks+vt = 16.5 KB.
// Outputs Linv = 1/l and PPOOL (fused pooled partials).
// ---------------------------------------------------------------------------
__global__ __launch_bounds__(256) void attn_ctx_k(
    const unsigned short* __restrict__ Q, const unsigned short* __restrict__ K,
    const unsigned short* __restrict__ VT,
    float* __restrict__ Linv, float* __restrict__ PPOOL)
{
    __shared__ unsigned short ks0[64 * 64];   // [kpos][hd]
    __shared__ unsigned short vt0[64 * 64];   // [d][kpos], staged from VT
    __shared__ float pp[4][64];               // per-wave pooled partials
    __shared__ float lsm[4][32];              // per-wave 1/l by local q-row

    // XCD swizzle: lin = (g&7) + 8*qb + 128*(g>>3)  (bijective, 1024 blocks)
    const int lin = blockIdx.x;
    const int g   = (lin & 7) | ((lin >> 7) << 3);   // bh index 0..63
    const int qb  = (lin >> 3) & 15;
    const int b   = g >> 4, h_ = g & 15;
    const int q0  = qb * 128;

    const size_t hoff = ((size_t)(b * H_ + h_)) * S_ * HD_;
    const unsigned short* Qh  = Q  + hoff;
    const unsigned short* Kh  = K  + hoff;
    const unsigned short* VTh = VT + hoff;   // [HD][S]

    const int tid = threadIdx.x, lane = tid & 63, wid = tid >> 6;
    const int srow = tid >> 3;       // 0..31
    const int skc  = (tid & 7) * 8;
    const int l31 = lane & 31, h = lane >> 5;

    // Q fragments (B-operand of QK^T): lane holds Q[q0w + l31][16kd + 8h + j]
    bf16x8 qf[4];
    #pragma unroll
    for (int kd = 0; kd < 4; ++kd)
        qf[kd] = *(const bf16x8*)&Qh[(size_t)(q0 + 32 * wid + l31) * HD_ + 16 * kd + 8 * h];

    f32x16 cacc[2] = {};   // [db]: ctx, q via reg-map, d = 32*db + l31
    float lp = 0.f;

    for (int kb = 0; kb < S_; kb += 64) {
        u16x8 ka[2], va[2];
        #pragma unroll
        for (int r = 0; r < 2; ++r) {
            int row = srow + 32 * r;
            ka[r] = *(const u16x8*)&Kh [(size_t)(kb + row) * HD_ + skc];
            va[r] = *(const u16x8*)&VTh[(size_t)row * S_ + kb + skc];
        }
        __syncthreads();   // everyone done reading previous ks0/vt0
        #pragma unroll
        for (int r = 0; r < 2; ++r) {
            int row = srow + 32 * r;
            *(u16x8*)swz64(ks0, row, skc) = ka[r];
            *(u16x8*)swz64(vt0, row, skc) = va[r];
        }
        __syncthreads();

        #pragma unroll
        for (int kr = 0; kr < 2; ++kr) {
            // S^T = K Q^T over 32 k-rows: sacc reg m = P[32kr + (m&3)+8*(m>>2)+4h][q=l31]
            f32x16 sacc = {};
            #pragma unroll
            for (int kd = 0; kd < 4; ++kd) {
                bf16x8 kf = *(const bf16x8*)swz64(ks0, 32 * kr + l31, 16 * kd + 8 * h);
                sacc = MFMA32(kf, qf[kd], sacc);
            }
            // exp + row-sum partial + pack to bf16 pairs (reg order = sigma order)
            float e[16];
            #pragma unroll
            for (int m = 0; m < 16; ++m) e[m] = exp2f(sacc[m]);
            #pragma unroll
            for (int m = 0; m < 16; m += 4)
                lp += (e[m] + e[m + 1]) + (e[m + 2] + e[m + 3]);
            unsigned int pk[8];
            #pragma unroll
            for (int j = 0; j < 8; ++j) pk[j] = cvtpk_bf16(e[2 * j], e[2 * j + 1]);

            // ctx += P @ V: A straight from pk regs; B slot-matched from vt.
            #pragma unroll
            for (int db = 0; db < 2; ++db) {
                const int d = 32 * db + l31;
                #pragma unroll
                for (int ks = 0; ks < 2; ++ks) {
                    s16x4 vlo = *(const s16x4*)swz64(vt0, d, 32 * kr + 16 * ks + 4 * h);
                    s16x4 vhi = *(const s16x4*)swz64(vt0, d, 32 * kr + 16 * ks + 8 + 4 * h);
                    bf16x8 vb = __builtin_shufflevector(vlo, vhi, 0, 1, 2, 3, 4, 5, 6, 7);
                    union { unsigned int u[4]; bf16x8 v; } af;
                    af.u[0] = pk[4 * ks + 0]; af.u[1] = pk[4 * ks + 1];
                    af.u[2] = pk[4 * ks + 2]; af.u[3] = pk[4 * ks + 3];
                    cacc[db] = MFMA32(af.v, vb, cacc[db]);
                }
            }
        }
    }

    // l: lanes l and l+32 hold complementary k-subsets of the same q=l31
    lp += __shfl_xor(lp, 32);
    if (lane < 32) {
        float inv = 1.0f / lp;
        Linv[((size_t)(b * H_ + h_)) * S_ + q0 + 32 * wid + lane] = inv;
        lsm[wid][lane] = inv;   // same-wave write->read below (wave-synchronous)
    }

    // fused pooling: pool[d] = sum_q cacc[q][d] * (1/l[q]); q from reg-map.
    float poold[2] = {};
    #pragma unroll
    for (int db = 0; db < 2; ++db)
        #pragma unroll
        for (int m = 0; m < 16; ++m)
            poold[db] = fmaf(cacc[db][m], lsm[wid][(m & 3) + 8 * (m >> 2) + 4 * h],
                             poold[db]);
    #pragma unroll
    for (int db = 0; db < 2; ++db) {
        poold[db] += __shfl_xor(poold[db], 32);
        if (lane < 32) pp[wid][32 * db + lane] = poold[db];
    }
    __syncthreads();
    if (tid < 64) {
        float s = pp[0][tid] + pp[1][tid] + pp[2][tid] + pp[3][tid];
        PPOOL[((size_t)(b * H_ + h_) * (S_ / 128) + qb) * 64 + tid] = s;
    }
}

// ---------------------------------------------------------------------------
// K3: attn_mean[b,q,k] = (1/16) sum_h exp2(s'_h) * Linv_h — second score
// pass.  LDS-staged Q (128x64) and K (64x64) per head; swapped MFMA ->
// dwordx4 stores; Linv is a multiply (no divides).
// ---------------------------------------------------------------------------
__global__ __launch_bounds__(256) void attn_mean_k(
    const unsigned short* __restrict__ Q, const unsigned short* __restrict__ K,
    const float* __restrict__ Linv, float* __restrict__ attn_out)
{
    __shared__ unsigned short qs[128][72];
    __shared__ unsigned short ksm[64][72];
    __shared__ float lsm[128];

    const int k0 = blockIdx.x * 64, q0 = blockIdx.y * 128, b = blockIdx.z;
    const int tid = threadIdx.x, lane = tid & 63, wid = tid >> 6;
    const int col_l = lane & 15, rgrp = lane >> 4;
    const int qrow = tid >> 1, qcol = (tid & 1) * 32;   // Q staging: 32 elems/thread
    const int krow = tid >> 2, kcol = (tid & 3) * 16;   // K staging: 16 elems/thread

    f32x4 macc[4][2] = {};   // [n: k-16-block][i: q-16-block]

    for (int h = 0; h < H_; ++h) {
        const size_t hoff = ((size_t)(b * H_ + h)) * S_ * HD_;
        const unsigned short* Qh = Q + hoff;
        const unsigned short* Kh = K + hoff;

        u16x8 qa[4], ka[2];
        #pragma unroll
        for (int j = 0; j < 4; ++j)
            qa[j] = *(const u16x8*)&Qh[(size_t)(q0 + qrow) * HD_ + qcol + 8 * j];
        #pragma unroll
        for (int j = 0; j < 2; ++j)
            ka[j] = *(const u16x8*)&Kh[(size_t)(k0 + krow) * HD_ + kcol + 8 * j];
        float lval = 0.f;
        if (tid < 128) lval = Linv[((size_t)(b * H_ + h)) * S_ + q0 + tid];

        __syncthreads();   // previous head's compute done
        #pragma unroll
        for (int j = 0; j < 4; ++j) *(u16x8*)&qs[qrow][qcol + 8 * j] = qa[j];
        #pragma unroll
        for (int j = 0; j < 2; ++j) *(u16x8*)&ksm[krow][kcol + 8 * j] = ka[j];
        if (tid < 128) lsm[tid] = lval;
        __syncthreads();

        bf16x8 qf[2][2];
        #pragma unroll
        for (int i = 0; i < 2; ++i)
            #pragma unroll
            for (int kd = 0; kd < 2; ++kd)
                qf[i][kd] = *(const bf16x8*)&qs[32 * wid + 16 * i + col_l][32 * kd + 8 * rgrp];

        float li0 = lsm[32 * wid + col_l] * 0.0625f;
        float li1 = lsm[32 * wid + 16 + col_l] * 0.0625f;

        #pragma unroll
        for (int n = 0; n < 4; ++n) {
            f32x4 s0 = {}, s1 = {};
            #pragma unroll
            for (int kd = 0; kd < 2; ++kd) {
                bf16x8 kf = *(const bf16x8*)&ksm[16 * n + col_l][32 * kd + 8 * rgrp];
                s0 = MFMA16(kf, qf[0][kd], s0);
                s1 = MFMA16(kf, qf[1][kd], s1);
            }
            #pragma unroll
            for (int r = 0; r < 4; ++r) {
                macc[n][0][r] = fmaf(exp2f(s0[r]), li0, macc[n][0][r]);
                macc[n][1][r] = fmaf(exp2f(s1[r]), li1, macc[n][1][r]);
            }
        }
    }

    #pragma unroll
    for (int n = 0; n < 4; ++n)
        #pragma unroll
        for (int i = 0; i < 2; ++i) {
            int q = q0 + 32 * wid + 16 * i + col_l;
            *(f32x4*)&attn_out[((size_t)b * S_ + q) * S_ + k0 + 16 * n + 4 * rgrp]
                = macc[n][i];
        }
}

// ---------------------------------------------------------------------------
// K4: out[b,j] = pooled[b,:] . wo[j,:] + bo[j], pooled reduced from PPOOL.
// ---------------------------------------------------------------------------
__global__ __launch_bounds__(256) void out_k(
    const float* __restrict__ PPOOL, const float* __restrict__ wo,
    const float* __restrict__ bo, float* __restrict__ out)
{
    __shared__ float psm[D_];
    const int b = blockIdx.x >> 2;
    for (int d = threadIdx.x; d < D_; d += 256) {
        const float* pp = PPOOL + ((size_t)(b * H_ + (d >> 6)) * (S_ / 128)) * 64 + (d & 63);
        float s = 0.f;
        #pragma unroll
        for (int qb = 0; qb < S_ / 128; ++qb) s += pp[qb * 64];
        psm[d] = s * (1.0f / S_);
    }
    __syncthreads();
    const int j = (blockIdx.x & 3) * 256 + threadIdx.x;
    float sum = bo[j];
    const float* wr = wo + (size_t)j * D_;
    for (int d = 0; d < D_; d += 4) {
        float4 w4 = *(const float4*)&wr[d];
        sum += psm[d] * w4.x + psm[d+1] * w4.y + psm[d+2] * w4.z + psm[d+3] * w4.w;
    }
    out[b * D_ + j] = sum;
}

// ---------------------------------------------------------------------------
extern "C" void kernel_launch(void* const* d_in, const int* in_sizes, int n_in,
                              void* d_out, int out_size, void* d_ws, size_t ws_size,
                              hipStream_t stream)
{
    const float* x  = (const float*)d_in[0];
    const float* wq = (const float*)d_in[1];
    const float* bq = (const float*)d_in[2];
    const float* wk = (const float*)d_in[3];
    const float* bk = (const float*)d_in[4];
    const float* wv = (const float*)d_in[5];
    const float* bv = (const float*)d_in[6];
    const float* wo = (const float*)d_in[7];
    const float* bo = (const float*)d_in[8];
    float* out = (float*)d_out;

    char* ws = (char*)d_ws;
    const size_t XN  = (size_t)M_ * D_;            // 8,388,608
    const size_t WN  = (size_t)D_ * D_;            // 1,048,576
    const size_t QN  = (size_t)B_ * H_ * S_ * HD_; // 8,388,608

    unsigned short* xb  = (unsigned short*)ws;                 ws += XN * 2;   // 16 MB
    unsigned short* wqb = (unsigned short*)ws;                 ws += WN * 2;   // 2 MB
    unsigned short* wkb = (unsigned short*)ws;                 ws += WN * 2;
    unsigned short* wvb = (unsigned short*)ws;                 ws += WN * 2;
    unsigned short* Qb  = (unsigned short*)ws;                 ws += QN * 2;   // 16 MB
    unsigned short* Kb  = (unsigned short*)ws;                 ws += QN * 2;
    unsigned short* VTb = (unsigned short*)ws;                 ws += QN * 2;   // [B][H][HD][S]
    float* Lb    = (float*)ws;                                 ws += (size_t)B_ * H_ * S_ * 4;
    float* PPOOL = (float*)ws;   // B*H*(S/128)*64 = 65536 floats = 256 KB

    cast_k<<<dim3(XN / 1024), 256, 0, stream>>>(x, xb, (int)XN);
    cast3_k<<<dim3(WN / 1024, 3), 256, 0, stream>>>(wq, wk, wv, wqb, wkb, wvb, (int)WN);

    qkv_gemm_k<<<dim3(M_ / 128, D_ / 128, 3), 256, 0, stream>>>(
        xb, wqb, wkb, wvb, bq, bk, bv, Qb, Kb, VTb);
    attn_ctx_k<<<dim3(1024), 256, 0, stream>>>(Qb, Kb, VTb, Lb, PPOOL);
    attn_mean_k<<<dim3(S_ / 64, S_ / 128, B_), 256, 0, stream>>>(Qb, Kb, Lb, out + B_ * D_);
    out_k<<<16, 256, 0, stream>>>(PPOOL, wo, bo, out);
}